// Round 4
// baseline (147.162 us; speedup 1.0000x reference)
//
#include <hip/hip_runtime.h>

#define N_PV 14000
#define N_OLM 12000
#define N_BIST 8000
#define TILE 256
#define NT 55                      // ceil(14000/256)
#define NTILES (NT * (NT + 1) / 2) // 1540 upper-triangular tiles (incl diagonal)

typedef float f32x4 __attribute__((ext_vector_type(4)));

// ================= symmetric tile kernel =================
// Block b < NTILES: processes upper tile (I,J). Reads the tile once.
//  - row parts (rows in block I): per-row 64-lane shuffle reduce -> slot [J][row]
//  - col parts (rows in block J, via symmetry): per-lane column accumulators,
//    cross-wave combine in LDS -> slot [I][col]   (off-diagonal tiles only)
// Block b == NTILES: drive = mean(pv_g_exc).
// Every (row, slot) pair is written exactly once => no init, no atomics.
__global__ __launch_bounds__(256) void tile_kernel(const float* __restrict__ W,
                                                   const float* __restrict__ V,
                                                   const float* __restrict__ pv_g_exc,
                                                   double* __restrict__ psum,
                                                   double* __restrict__ pdot,
                                                   float* __restrict__ drive_p) {
    const int tid = threadIdx.x;
    const int wid = tid >> 6, lane = tid & 63;

    if (blockIdx.x == NTILES) {
        __shared__ double ls[4];
        double s = 0.0;
        for (int i = tid; i < N_PV; i += 256) s += (double)pv_g_exc[i];
        for (int off = 32; off > 0; off >>= 1) s += __shfl_down(s, off, 64);
        if (lane == 0) ls[wid] = s;
        __syncthreads();
        if (tid == 0)
            drive_p[0] = (float)(((ls[0] + ls[1]) + (ls[2] + ls[3])) / (double)N_PV);
        return;
    }

    __shared__ double lcs[4][TILE], lcd[4][TILE];   // 16 KB

    // decode linear tile index -> (I,J), J >= I
    int rem = blockIdx.x, I = 0;
    while (rem >= NT - I) { rem -= NT - I; ++I; }
    const int J = I + rem;

    const int rows0 = I * TILE, cols0 = J * TILE;
    const int nrows = min(TILE, N_PV - rows0);
    const int ncols = min(TILE, N_PV - cols0);
    const bool diag = (I == J);

    const bool colok = (lane * 4) < ncols;          // N_PV % 4 == 0 -> whole float4 valid
    double vc0 = 0, vc1 = 0, vc2 = 0, vc3 = 0;      // V at this lane's 4 columns
    if (colok) {
        const f32x4 v = *(const f32x4*)(V + cols0 + lane * 4);
        vc0 = v.x; vc1 = v.y; vc2 = v.z; vc3 = v.w;
    }
    double cs0 = 0, cs1 = 0, cs2 = 0, cs3 = 0;      // column accumulators (sum)
    double cd0 = 0, cd1 = 0, cd2 = 0, cd3 = 0;      // column accumulators (dot with V[row])

    const int rb = wid * 64;
    const int re = min(rb + 64, nrows);
#pragma unroll 2
    for (int r = rb; r < re; ++r) {
        f32x4 w = {0.f, 0.f, 0.f, 0.f};
        if (colok)
            w = __builtin_nontemporal_load(
                    (const f32x4*)(W + (size_t)(rows0 + r) * N_PV + cols0) + lane);
        const double w0 = w.x, w1 = w.y, w2 = w.z, w3 = w.w;
        double rs = (w0 + w1) + (w2 + w3);
        double rd = (w0 * vc0 + w1 * vc1) + (w2 * vc2 + w3 * vc3);
        if (!diag) {
            const double vr = (double)V[rows0 + r];  // wave-uniform
            cs0 += w0; cs1 += w1; cs2 += w2; cs3 += w3;
            cd0 += w0 * vr; cd1 += w1 * vr; cd2 += w2 * vr; cd3 += w3 * vr;
        }
        for (int off = 32; off > 0; off >>= 1) {
            rs += __shfl_down(rs, off, 64);
            rd += __shfl_down(rd, off, 64);
        }
        if (lane == 0) {
            psum[(size_t)J * N_PV + rows0 + r] = rs;
            pdot[(size_t)J * N_PV + rows0 + r] = rd;
        }
    }

    if (!diag) {
        lcs[wid][lane * 4 + 0] = cs0; lcs[wid][lane * 4 + 1] = cs1;
        lcs[wid][lane * 4 + 2] = cs2; lcs[wid][lane * 4 + 3] = cs3;
        lcd[wid][lane * 4 + 0] = cd0; lcd[wid][lane * 4 + 1] = cd1;
        lcd[wid][lane * 4 + 2] = cd2; lcd[wid][lane * 4 + 3] = cd3;
        __syncthreads();
        const int c = tid;
        if (c < ncols) {
            const double s = (lcs[0][c] + lcs[1][c]) + (lcs[2][c] + lcs[3][c]);
            const double d = (lcd[0][c] + lcd[1][c]) + (lcd[2][c] + lcd[3][c]);
            psum[(size_t)I * N_PV + cols0 + c] = s;
            pdot[(size_t)I * N_PV + cols0 + c] = d;
        }
    }
}

// ============ fallback (R3): full-read one block per row ============
__global__ __launch_bounds__(256) void row_kernel(const float* __restrict__ W,
                                                  const float* __restrict__ V,
                                                  const float* __restrict__ pv_g_exc,
                                                  float* __restrict__ rowsum,
                                                  float* __restrict__ rowdot,
                                                  float* __restrict__ drive_p) {
    __shared__ double ls[4], ld[4];
    const int wid = threadIdx.x >> 6, lane = threadIdx.x & 63;
    const int row = blockIdx.x;
    if (row == N_PV) {
        double s = 0.0;
        for (int i = threadIdx.x; i < N_PV; i += 256) s += (double)pv_g_exc[i];
        for (int off = 32; off > 0; off >>= 1) s += __shfl_down(s, off, 64);
        if (lane == 0) ls[wid] = s;
        __syncthreads();
        if (threadIdx.x == 0)
            drive_p[0] = (float)(((ls[0] + ls[1]) + (ls[2] + ls[3])) / (double)N_PV);
        return;
    }
    const f32x4* __restrict__ wr = (const f32x4*)(W + (size_t)row * N_PV);
    const f32x4* __restrict__ vv = (const f32x4*)V;
    double s0 = 0.0, d0 = 0.0, s1 = 0.0, d1 = 0.0;
    int j = threadIdx.x;
    const int NV = N_PV / 4;
    for (; j + 256 < NV; j += 512) {
        const f32x4 w0 = __builtin_nontemporal_load(&wr[j]);
        const f32x4 v0 = vv[j];
        const f32x4 w1 = __builtin_nontemporal_load(&wr[j + 256]);
        const f32x4 v1 = vv[j + 256];
        s0 += (double)w0.x + (double)w0.y + (double)w0.z + (double)w0.w;
        d0 += (double)w0.x * (double)v0.x + (double)w0.y * (double)v0.y
            + (double)w0.z * (double)v0.z + (double)w0.w * (double)v0.w;
        s1 += (double)w1.x + (double)w1.y + (double)w1.z + (double)w1.w;
        d1 += (double)w1.x * (double)v1.x + (double)w1.y * (double)v1.y
            + (double)w1.z * (double)v1.z + (double)w1.w * (double)v1.w;
    }
    for (; j < NV; j += 256) {
        const f32x4 w0 = __builtin_nontemporal_load(&wr[j]);
        const f32x4 v0 = vv[j];
        s0 += (double)w0.x + (double)w0.y + (double)w0.z + (double)w0.w;
        d0 += (double)w0.x * (double)v0.x + (double)w0.y * (double)v0.y
            + (double)w0.z * (double)v0.z + (double)w0.w * (double)v0.w;
    }
    double s = s0 + s1, d = d0 + d1;
    for (int off = 32; off > 0; off >>= 1) {
        s += __shfl_down(s, off, 64);
        d += __shfl_down(d, off, 64);
    }
    if (lane == 0) { ls[wid] = s; ld[wid] = d; }
    __syncthreads();
    if (threadIdx.x == 0) {
        rowsum[row] = (float)((ls[0] + ls[1]) + (ls[2] + ls[3]));
        rowdot[row] = (float)((ld[0] + ld[1]) + (ld[2] + ld[3]));
    }
}

// ================= fused LIF step =================
// mode==1: PV reduces the 55 f64 tile partials (fixed order, deterministic).
// mode==0: PV reads precomputed f32 rowsum/rowdot (fallback path).
__global__ __launch_bounds__(256) void lif_kernel(
    const float* __restrict__ pv_g_exc,  const float* __restrict__ pv_g_inh,
    const float* __restrict__ olm_g_exc, const float* __restrict__ olm_g_inh,
    const float* __restrict__ bi_g_exc,  const float* __restrict__ bi_g_inh,
    const float* __restrict__ pv_V,  const float* __restrict__ pv_tau,
    const float* __restrict__ pv_vth, const float* __restrict__ pv_gL,
    const float* __restrict__ pv_w,
    const float* __restrict__ olm_V,  const float* __restrict__ olm_tau,
    const float* __restrict__ olm_vth, const float* __restrict__ olm_gL,
    const float* __restrict__ olm_w,
    const float* __restrict__ bi_V,  const float* __restrict__ bi_tau,
    const float* __restrict__ bi_vth, const float* __restrict__ bi_gL,
    const float* __restrict__ bi_w,
    const double* __restrict__ psum, const double* __restrict__ pdot,
    const float* __restrict__ rowsum, const float* __restrict__ rowdot,
    const float* __restrict__ drive_p, int mode,
    float* __restrict__ out) {
#pragma clang fp contract(off)
    const int i = blockIdx.x * 256 + threadIdx.x;
    const float E_E = 3.0f, E_I = -0.5f, E_NMDA = 3.0f;
    if (i < N_PV) {
        float gt, rd_f;
        if (mode == 1) {
            double S = 0.0, D = 0.0;
#pragma unroll
            for (int s = 0; s < NT; ++s) {
                S += psum[(size_t)s * N_PV + i];
                D += pdot[(size_t)s * N_PV + i];
            }
            gt = (float)S; rd_f = (float)D;
        } else {
            gt = rowsum[i]; rd_f = rowdot[i];
        }
        const float drive  = drive_p[0];
        const float gain   = fminf(1.0f, drive / 0.1f);
        const float active = (drive > 0.01f) ? 1.0f : 0.0f;
        const float Egap = rd_f / (gt + 1e-9f);
        const float ggap = gt * gain * active;
        const float V   = pv_V[i];
        const float gex = pv_g_exc[i];
        const float ga  = gex * 0.7f;
        const float gn  = gex * 0.3f;
        const float gi  = pv_g_inh[i];
        const float syn = (ga * (E_E - V) + gn * (E_NMDA - V) + gi * (E_I - V)
                           + ggap * (Egap - V) - pv_w[i]) / pv_gL[i];
        const float Vn = V + (1.0f / pv_tau[i]) * ((0.0f - V) + syn);
        out[i] = (Vn >= pv_vth[i]) ? 1.0f : 0.0f;
    } else if (i < N_PV + N_OLM) {
        const int j = i - N_PV;
        const float V   = olm_V[j];
        const float gex = olm_g_exc[j];
        const float ga  = gex * 0.95f;
        const float gn  = gex * 0.05f;
        const float gi  = olm_g_inh[j];
        const float syn = (ga * (E_E - V) + gn * (E_NMDA - V) + gi * (E_I - V)
                           + 0.0f * (0.0f - V) - olm_w[j]) / olm_gL[j];
        const float Vn = V + (1.0f / olm_tau[j]) * ((0.0f - V) + syn);
        out[i] = (Vn >= olm_vth[j]) ? 1.0f : 0.0f;
    } else if (i < N_PV + N_OLM + N_BIST) {
        const int j = i - N_PV - N_OLM;
        const float V   = bi_V[j];
        const float gex = bi_g_exc[j];
        const float ga  = gex * 0.95f;
        const float gn  = gex * 0.05f;
        const float gi  = bi_g_inh[j];
        const float syn = (ga * (E_E - V) + gn * (E_NMDA - V) + gi * (E_I - V)
                           + 0.0f * (0.0f - V) - bi_w[j]) / bi_gL[j];
        const float Vn = V + (1.0f / bi_tau[j]) * ((0.0f - V) + syn);
        out[i] = (Vn >= bi_vth[j]) ? 1.0f : 0.0f;
    }
}

extern "C" void kernel_launch(void* const* d_in, const int* in_sizes, int n_in,
                              void* d_out, int out_size, void* d_ws, size_t ws_size,
                              hipStream_t stream) {
    const float* pv_g_exc   = (const float*)d_in[0];
    const float* pv_g_inh   = (const float*)d_in[1];
    const float* olm_g_exc  = (const float*)d_in[2];
    const float* olm_g_inh  = (const float*)d_in[3];
    const float* bist_g_exc = (const float*)d_in[4];
    const float* bist_g_inh = (const float*)d_in[5];
    const float* W_gap      = (const float*)d_in[6];
    const float* pv_V       = (const float*)d_in[7];
    const float* pv_tau     = (const float*)d_in[8];
    const float* pv_vth     = (const float*)d_in[9];
    const float* pv_gL      = (const float*)d_in[10];
    // d_in[11] = pv_vreset (unused: spikes don't depend on it)
    const float* pv_w       = (const float*)d_in[12];
    const float* olm_V      = (const float*)d_in[13];
    const float* olm_tau    = (const float*)d_in[14];
    const float* olm_vth    = (const float*)d_in[15];
    const float* olm_gL     = (const float*)d_in[16];
    // d_in[17] = olm_vreset (unused)
    const float* olm_w      = (const float*)d_in[18];
    const float* bist_V     = (const float*)d_in[19];
    const float* bist_tau   = (const float*)d_in[20];
    const float* bist_vth   = (const float*)d_in[21];
    const float* bist_gL    = (const float*)d_in[22];
    // d_in[23] = bist_vreset (unused)
    const float* bist_w     = (const float*)d_in[24];

    const size_t npart = (size_t)NT * N_PV;                 // 770,000 doubles
    const size_t need  = 2 * npart * sizeof(double) + 64;   // ~12.32 MB
    const int total = N_PV + N_OLM + N_BIST;

    if (ws_size >= need) {
        double* psum   = (double*)d_ws;
        double* pdot   = psum + npart;
        float*  drive_p = (float*)(pdot + npart);
        hipLaunchKernelGGL(tile_kernel, dim3(NTILES + 1), dim3(256), 0, stream,
                           W_gap, pv_V, pv_g_exc, psum, pdot, drive_p);
        hipLaunchKernelGGL(lif_kernel, dim3((total + 255) / 256), dim3(256), 0, stream,
                           pv_g_exc, pv_g_inh, olm_g_exc, olm_g_inh,
                           bist_g_exc, bist_g_inh,
                           pv_V, pv_tau, pv_vth, pv_gL, pv_w,
                           olm_V, olm_tau, olm_vth, olm_gL, olm_w,
                           bist_V, bist_tau, bist_vth, bist_gL, bist_w,
                           psum, pdot, (const float*)nullptr, (const float*)nullptr,
                           drive_p, 1, (float*)d_out);
    } else {
        float* ws      = (float*)d_ws;
        float* rowsum  = ws;
        float* rowdot  = ws + N_PV;
        float* drive_p = ws + 2 * N_PV;
        hipLaunchKernelGGL(row_kernel, dim3(N_PV + 1), dim3(256), 0, stream,
                           W_gap, pv_V, pv_g_exc, rowsum, rowdot, drive_p);
        hipLaunchKernelGGL(lif_kernel, dim3((total + 255) / 256), dim3(256), 0, stream,
                           pv_g_exc, pv_g_inh, olm_g_exc, olm_g_inh,
                           bist_g_exc, bist_g_inh,
                           pv_V, pv_tau, pv_vth, pv_gL, pv_w,
                           olm_V, olm_tau, olm_vth, olm_gL, olm_w,
                           bist_V, bist_tau, bist_vth, bist_gL, bist_w,
                           (const double*)nullptr, (const double*)nullptr,
                           rowsum, rowdot, drive_p, 0, (float*)d_out);
    }
}

// Round 5
// 103.410 us; speedup vs baseline: 1.4231x; 1.4231x over previous
//
#include <hip/hip_runtime.h>

#define N_PV 14000
#define N_OLM 12000
#define N_BIST 8000
#define TILE 128
#define NT 110                      // ceil(14000/128)
#define NTILES (NT * (NT + 1) / 2)  // 6105 upper-triangular tiles (incl diagonal)

typedef float f32x2 __attribute__((ext_vector_type(2)));
typedef float f32x4 __attribute__((ext_vector_type(4)));

// ================= symmetric tile kernel (batched-butterfly) =================
// Block b < NTILES: upper tile (I,J), 128x128. Reads the tile once (f32x2/lane).
//  - row parts (rows of block I) -> slot [J][row]: 16-row batched butterfly
//    (17 f32 shuffles per quantity per 16 rows instead of 6 per row)
//  - col parts (rows of block J via symmetry) -> slot [I][col]: per-lane f32
//    accumulators, 4-wave combine through 4 KB LDS. Off-diagonal only.
// Block b == NTILES: drive = mean(pv_g_exc).
// Every (row,slot) is written exactly once => no init, no atomics, deterministic.
__global__ __launch_bounds__(256) void tile_kernel(const float* __restrict__ W,
                                                   const float* __restrict__ V,
                                                   const float* __restrict__ pv_g_exc,
                                                   float* __restrict__ psum,
                                                   float* __restrict__ pdot,
                                                   float* __restrict__ drive_p) {
    const int tid = threadIdx.x;
    const int wid = tid >> 6, lane = tid & 63;

    if (blockIdx.x == NTILES) {
        __shared__ double dls[4];
        double s = 0.0;
        for (int i = tid; i < N_PV; i += 256) s += (double)pv_g_exc[i];
        for (int off = 32; off > 0; off >>= 1) s += __shfl_down(s, off, 64);
        if (lane == 0) dls[wid] = s;
        __syncthreads();
        if (tid == 0)
            drive_p[0] = (float)(((dls[0] + dls[1]) + (dls[2] + dls[3])) / (double)N_PV);
        return;
    }

    __shared__ float lcs[4][TILE], lcd[4][TILE];   // 4 KB

    // decode linear tile index -> (I,J), J >= I
    int rem = blockIdx.x, I = 0;
    while (rem >= NT - I) { rem -= NT - I; ++I; }
    const int J = I + rem;

    const int rows0 = I * TILE, cols0 = J * TILE;
    const int nrows = min(TILE, N_PV - rows0);
    const int ncols = min(TILE, N_PV - cols0);
    const bool diag = (I == J);

    const bool colok = (2 * lane) < ncols;      // N_PV even -> whole f32x2 valid
    float vcx = 0.f, vcy = 0.f;
    if (colok) {
        const f32x2 v = *(const f32x2*)(V + cols0 + 2 * lane);
        vcx = v.x; vcy = v.y;
    }
    float cs0 = 0.f, cs1 = 0.f, cd0 = 0.f, cd1 = 0.f;   // column accumulators

    const float* __restrict__ Wt = W + (size_t)rows0 * N_PV + cols0 + 2 * lane;
    const int b0 = lane & 1, b1 = (lane >> 1) & 1, b2 = (lane >> 2) & 1, b3 = (lane >> 3) & 1;
    const int wbase = wid * 32;                  // 32 rows per wave, 2 passes of 16

#pragma unroll
    for (int pass = 0; pass < 2; ++pass) {
        const int rb = wbase + pass * 16;
        // ---- issue all 16 row loads up front (independent -> deep MLP) ----
        f32x2 w[16];
#pragma unroll
        for (int k = 0; k < 16; ++k) {
            const int r = rb + k;
            f32x2 z = {0.f, 0.f};
            w[k] = (colok && r < nrows)
                 ? __builtin_nontemporal_load((const f32x2*)(Wt + (size_t)r * N_PV))
                 : z;
        }
        // ---- per-row partials (all f32) + column accumulation ----
        float rs[16], rd[16];
#pragma unroll
        for (int k = 0; k < 16; ++k) {
            const float wx = w[k].x, wy = w[k].y;
            rs[k] = wx + wy;
            rd[k] = wx * vcx + wy * vcy;
            if (!diag) {
                const int r = rb + k;
                const float vr = (r < nrows) ? V[rows0 + r] : 0.f;
                cs0 += wx; cs1 += wy;
                cd0 += wx * vr; cd1 += wy * vr;
            }
        }
        // ---- batched butterfly: 16 rows reduced with 17 shuffles/quantity ----
#pragma unroll
        for (int i = 0; i < 8; ++i) {   // dist 1: row-bit3 = b0
            const float ss = b0 ? rs[i] : rs[i + 8];
            const float sd = b0 ? rd[i] : rd[i + 8];
            const float ts = __shfl_xor(ss, 1, 64);
            const float td = __shfl_xor(sd, 1, 64);
            rs[i] = (b0 ? rs[i + 8] : rs[i]) + ts;
            rd[i] = (b0 ? rd[i + 8] : rd[i]) + td;
        }
#pragma unroll
        for (int i = 0; i < 4; ++i) {   // dist 2: row-bit2 = b1
            const float ss = b1 ? rs[i] : rs[i + 4];
            const float sd = b1 ? rd[i] : rd[i + 4];
            const float ts = __shfl_xor(ss, 2, 64);
            const float td = __shfl_xor(sd, 2, 64);
            rs[i] = (b1 ? rs[i + 4] : rs[i]) + ts;
            rd[i] = (b1 ? rd[i + 4] : rd[i]) + td;
        }
#pragma unroll
        for (int i = 0; i < 2; ++i) {   // dist 4: row-bit1 = b2
            const float ss = b2 ? rs[i] : rs[i + 2];
            const float sd = b2 ? rd[i] : rd[i + 2];
            const float ts = __shfl_xor(ss, 4, 64);
            const float td = __shfl_xor(sd, 4, 64);
            rs[i] = (b2 ? rs[i + 2] : rs[i]) + ts;
            rd[i] = (b2 ? rd[i + 2] : rd[i]) + td;
        }
        {                               // dist 8: row-bit0 = b3
            const float ss = b3 ? rs[0] : rs[1];
            const float sd = b3 ? rd[0] : rd[1];
            const float ts = __shfl_xor(ss, 8, 64);
            const float td = __shfl_xor(sd, 8, 64);
            rs[0] = (b3 ? rs[1] : rs[0]) + ts;
            rd[0] = (b3 ? rd[1] : rd[0]) + td;
        }
        rs[0] += __shfl_xor(rs[0], 16, 64);  rd[0] += __shfl_xor(rd[0], 16, 64);
        rs[0] += __shfl_xor(rs[0], 32, 64);  rd[0] += __shfl_xor(rd[0], 32, 64);

        if (lane < 16) {
            const int rl = (b0 << 3) | (b1 << 2) | (b2 << 1) | b3;  // bit-reversed lane
            const int r = rb + rl;
            if (r < nrows) {
                psum[(size_t)J * N_PV + rows0 + r] = rs[0];
                pdot[(size_t)J * N_PV + rows0 + r] = rd[0];
            }
        }
    }

    if (!diag) {
        lcs[wid][2 * lane] = cs0; lcs[wid][2 * lane + 1] = cs1;
        lcd[wid][2 * lane] = cd0; lcd[wid][2 * lane + 1] = cd1;
        __syncthreads();
        const int c = tid;
        if (c < TILE && c < ncols) {
            const float s = (lcs[0][c] + lcs[1][c]) + (lcs[2][c] + lcs[3][c]);
            const float d = (lcd[0][c] + lcd[1][c]) + (lcd[2][c] + lcd[3][c]);
            psum[(size_t)I * N_PV + cols0 + c] = s;
            pdot[(size_t)I * N_PV + cols0 + c] = d;
        }
    }
}

// ============ fallback (R3): full-read one block per row ============
__global__ __launch_bounds__(256) void row_kernel(const float* __restrict__ W,
                                                  const float* __restrict__ V,
                                                  const float* __restrict__ pv_g_exc,
                                                  float* __restrict__ rowsum,
                                                  float* __restrict__ rowdot,
                                                  float* __restrict__ drive_p) {
    __shared__ double ls[4], ld[4];
    const int wid = threadIdx.x >> 6, lane = threadIdx.x & 63;
    const int row = blockIdx.x;
    if (row == N_PV) {
        double s = 0.0;
        for (int i = threadIdx.x; i < N_PV; i += 256) s += (double)pv_g_exc[i];
        for (int off = 32; off > 0; off >>= 1) s += __shfl_down(s, off, 64);
        if (lane == 0) ls[wid] = s;
        __syncthreads();
        if (threadIdx.x == 0)
            drive_p[0] = (float)(((ls[0] + ls[1]) + (ls[2] + ls[3])) / (double)N_PV);
        return;
    }
    const f32x4* __restrict__ wr = (const f32x4*)(W + (size_t)row * N_PV);
    const f32x4* __restrict__ vv = (const f32x4*)V;
    double s0 = 0.0, d0 = 0.0, s1 = 0.0, d1 = 0.0;
    int j = threadIdx.x;
    const int NV = N_PV / 4;
    for (; j + 256 < NV; j += 512) {
        const f32x4 w0 = __builtin_nontemporal_load(&wr[j]);
        const f32x4 v0 = vv[j];
        const f32x4 w1 = __builtin_nontemporal_load(&wr[j + 256]);
        const f32x4 v1 = vv[j + 256];
        s0 += (double)w0.x + (double)w0.y + (double)w0.z + (double)w0.w;
        d0 += (double)w0.x * (double)v0.x + (double)w0.y * (double)v0.y
            + (double)w0.z * (double)v0.z + (double)w0.w * (double)v0.w;
        s1 += (double)w1.x + (double)w1.y + (double)w1.z + (double)w1.w;
        d1 += (double)w1.x * (double)v1.x + (double)w1.y * (double)v1.y
            + (double)w1.z * (double)v1.z + (double)w1.w * (double)v1.w;
    }
    for (; j < NV; j += 256) {
        const f32x4 w0 = __builtin_nontemporal_load(&wr[j]);
        const f32x4 v0 = vv[j];
        s0 += (double)w0.x + (double)w0.y + (double)w0.z + (double)w0.w;
        d0 += (double)w0.x * (double)v0.x + (double)w0.y * (double)v0.y
            + (double)w0.z * (double)v0.z + (double)w0.w * (double)v0.w;
    }
    double s = s0 + s1, d = d0 + d1;
    for (int off = 32; off > 0; off >>= 1) {
        s += __shfl_down(s, off, 64);
        d += __shfl_down(d, off, 64);
    }
    if (lane == 0) { ls[wid] = s; ld[wid] = d; }
    __syncthreads();
    if (threadIdx.x == 0) {
        rowsum[row] = (float)((ls[0] + ls[1]) + (ls[2] + ls[3]));
        rowdot[row] = (float)((ld[0] + ld[1]) + (ld[2] + ld[3]));
    }
}

// ================= fused LIF step =================
// mode==1: PV reduces the NT f32 tile partials in f64, fixed order (deterministic).
// mode==0: PV reads precomputed f32 rowsum/rowdot (fallback path).
__global__ __launch_bounds__(256) void lif_kernel(
    const float* __restrict__ pv_g_exc,  const float* __restrict__ pv_g_inh,
    const float* __restrict__ olm_g_exc, const float* __restrict__ olm_g_inh,
    const float* __restrict__ bi_g_exc,  const float* __restrict__ bi_g_inh,
    const float* __restrict__ pv_V,  const float* __restrict__ pv_tau,
    const float* __restrict__ pv_vth, const float* __restrict__ pv_gL,
    const float* __restrict__ pv_w,
    const float* __restrict__ olm_V,  const float* __restrict__ olm_tau,
    const float* __restrict__ olm_vth, const float* __restrict__ olm_gL,
    const float* __restrict__ olm_w,
    const float* __restrict__ bi_V,  const float* __restrict__ bi_tau,
    const float* __restrict__ bi_vth, const float* __restrict__ bi_gL,
    const float* __restrict__ bi_w,
    const float* __restrict__ psum, const float* __restrict__ pdot,
    const float* __restrict__ rowsum, const float* __restrict__ rowdot,
    const float* __restrict__ drive_p, int mode,
    float* __restrict__ out) {
#pragma clang fp contract(off)
    const int i = blockIdx.x * 256 + threadIdx.x;
    const float E_E = 3.0f, E_I = -0.5f, E_NMDA = 3.0f;
    if (i < N_PV) {
        float gt, rd_f;
        if (mode == 1) {
            double S = 0.0, D = 0.0;
#pragma unroll 5
            for (int s = 0; s < NT; ++s) {
                S += (double)psum[(size_t)s * N_PV + i];
                D += (double)pdot[(size_t)s * N_PV + i];
            }
            gt = (float)S; rd_f = (float)D;
        } else {
            gt = rowsum[i]; rd_f = rowdot[i];
        }
        const float drive  = drive_p[0];
        const float gain   = fminf(1.0f, drive / 0.1f);
        const float active = (drive > 0.01f) ? 1.0f : 0.0f;
        const float Egap = rd_f / (gt + 1e-9f);
        const float ggap = gt * gain * active;
        const float V   = pv_V[i];
        const float gex = pv_g_exc[i];
        const float ga  = gex * 0.7f;
        const float gn  = gex * 0.3f;
        const float gi  = pv_g_inh[i];
        const float syn = (ga * (E_E - V) + gn * (E_NMDA - V) + gi * (E_I - V)
                           + ggap * (Egap - V) - pv_w[i]) / pv_gL[i];
        const float Vn = V + (1.0f / pv_tau[i]) * ((0.0f - V) + syn);
        out[i] = (Vn >= pv_vth[i]) ? 1.0f : 0.0f;
    } else if (i < N_PV + N_OLM) {
        const int j = i - N_PV;
        const float V   = olm_V[j];
        const float gex = olm_g_exc[j];
        const float ga  = gex * 0.95f;
        const float gn  = gex * 0.05f;
        const float gi  = olm_g_inh[j];
        const float syn = (ga * (E_E - V) + gn * (E_NMDA - V) + gi * (E_I - V)
                           + 0.0f * (0.0f - V) - olm_w[j]) / olm_gL[j];
        const float Vn = V + (1.0f / olm_tau[j]) * ((0.0f - V) + syn);
        out[i] = (Vn >= olm_vth[j]) ? 1.0f : 0.0f;
    } else if (i < N_PV + N_OLM + N_BIST) {
        const int j = i - N_PV - N_OLM;
        const float V   = bi_V[j];
        const float gex = bi_g_exc[j];
        const float ga  = gex * 0.95f;
        const float gn  = gex * 0.05f;
        const float gi  = bi_g_inh[j];
        const float syn = (ga * (E_E - V) + gn * (E_NMDA - V) + gi * (E_I - V)
                           + 0.0f * (0.0f - V) - bi_w[j]) / bi_gL[j];
        const float Vn = V + (1.0f / bi_tau[j]) * ((0.0f - V) + syn);
        out[i] = (Vn >= bi_vth[j]) ? 1.0f : 0.0f;
    }
}

extern "C" void kernel_launch(void* const* d_in, const int* in_sizes, int n_in,
                              void* d_out, int out_size, void* d_ws, size_t ws_size,
                              hipStream_t stream) {
    const float* pv_g_exc   = (const float*)d_in[0];
    const float* pv_g_inh   = (const float*)d_in[1];
    const float* olm_g_exc  = (const float*)d_in[2];
    const float* olm_g_inh  = (const float*)d_in[3];
    const float* bist_g_exc = (const float*)d_in[4];
    const float* bist_g_inh = (const float*)d_in[5];
    const float* W_gap      = (const float*)d_in[6];
    const float* pv_V       = (const float*)d_in[7];
    const float* pv_tau     = (const float*)d_in[8];
    const float* pv_vth     = (const float*)d_in[9];
    const float* pv_gL      = (const float*)d_in[10];
    // d_in[11] = pv_vreset (unused: spikes don't depend on it)
    const float* pv_w       = (const float*)d_in[12];
    const float* olm_V      = (const float*)d_in[13];
    const float* olm_tau    = (const float*)d_in[14];
    const float* olm_vth    = (const float*)d_in[15];
    const float* olm_gL     = (const float*)d_in[16];
    // d_in[17] = olm_vreset (unused)
    const float* olm_w      = (const float*)d_in[18];
    const float* bist_V     = (const float*)d_in[19];
    const float* bist_tau   = (const float*)d_in[20];
    const float* bist_vth   = (const float*)d_in[21];
    const float* bist_gL    = (const float*)d_in[22];
    // d_in[23] = bist_vreset (unused)
    const float* bist_w     = (const float*)d_in[24];

    const size_t npart = (size_t)NT * N_PV;                // 1,540,000 floats
    const size_t need  = 2 * npart * sizeof(float) + 64;   // ~12.32 MB
    const int total = N_PV + N_OLM + N_BIST;

    if (ws_size >= need) {
        float* psum    = (float*)d_ws;
        float* pdot    = psum + npart;
        float* drive_p = pdot + npart;
        hipLaunchKernelGGL(tile_kernel, dim3(NTILES + 1), dim3(256), 0, stream,
                           W_gap, pv_V, pv_g_exc, psum, pdot, drive_p);
        hipLaunchKernelGGL(lif_kernel, dim3((total + 255) / 256), dim3(256), 0, stream,
                           pv_g_exc, pv_g_inh, olm_g_exc, olm_g_inh,
                           bist_g_exc, bist_g_inh,
                           pv_V, pv_tau, pv_vth, pv_gL, pv_w,
                           olm_V, olm_tau, olm_vth, olm_gL, olm_w,
                           bist_V, bist_tau, bist_vth, bist_gL, bist_w,
                           psum, pdot, (const float*)nullptr, (const float*)nullptr,
                           drive_p, 1, (float*)d_out);
    } else {
        float* ws      = (float*)d_ws;
        float* rowsum  = ws;
        float* rowdot  = ws + N_PV;
        float* drive_p = ws + 2 * N_PV;
        hipLaunchKernelGGL(row_kernel, dim3(N_PV + 1), dim3(256), 0, stream,
                           W_gap, pv_V, pv_g_exc, rowsum, rowdot, drive_p);
        hipLaunchKernelGGL(lif_kernel, dim3((total + 255) / 256), dim3(256), 0, stream,
                           pv_g_exc, pv_g_inh, olm_g_exc, olm_g_inh,
                           bist_g_exc, bist_g_inh,
                           pv_V, pv_tau, pv_vth, pv_gL, pv_w,
                           olm_V, olm_tau, olm_vth, olm_gL, olm_w,
                           bist_V, bist_tau, bist_vth, bist_gL, bist_w,
                           (const float*)nullptr, (const float*)nullptr,
                           rowsum, rowdot, drive_p, 0, (float*)d_out);
    }
}

// Round 6
// 83.631 us; speedup vs baseline: 1.7596x; 1.2365x over previous
//
#include <hip/hip_runtime.h>

#define N_PV 14000
#define N_OLM 12000
#define N_BIST 8000
#define TILE 256
#define NT 55                      // ceil(14000/256)
#define NTILES (NT * (NT + 1) / 2) // 1540 upper-triangular tiles (incl diagonal)

typedef float f32x4 __attribute__((ext_vector_type(4)));

// ---- tile body: FULL=true -> interior tile, no bounds predicates ----
template<bool FULL>
__device__ __forceinline__ void tile_body(const float* __restrict__ W,
                                          const float* __restrict__ V,
                                          float* __restrict__ psum,
                                          float* __restrict__ pdot,
                                          int I, int J, int rows0, int cols0,
                                          int nrows, int ncols, bool diag,
                                          int wid, int lane,
                                          float (*lcs)[TILE], float (*lcd)[TILE]) {
    const bool colok = FULL || (lane * 4 < ncols);   // ncols % 4 == 0 always
    f32x4 vc = {0.f, 0.f, 0.f, 0.f};
    if (colok) vc = *(const f32x4*)(V + cols0 + 4 * lane);
    float cs0 = 0.f, cs1 = 0.f, cs2 = 0.f, cs3 = 0.f;
    float cd0 = 0.f, cd1 = 0.f, cd2 = 0.f, cd3 = 0.f;

    const float* __restrict__ Wt = W + (size_t)rows0 * N_PV + cols0 + 4 * lane;
    const int b0 = lane & 1, b1 = (lane >> 1) & 1, b2 = (lane >> 2) & 1, b3 = (lane >> 3) & 1;
    const int wbase = wid * 64;                      // 64 rows per wave: 4 passes of 16

#pragma unroll
    for (int pass = 0; pass < 4; ++pass) {
        const int rb = wbase + pass * 16;
        // ---- issue all 16 row loads up front (16 outstanding 1KB loads) ----
        f32x4 w[16];
#pragma unroll
        for (int k = 0; k < 16; ++k) {
            const int r = rb + k;
            f32x4 z = {0.f, 0.f, 0.f, 0.f};
            w[k] = (FULL || (colok && r < nrows))
                 ? __builtin_nontemporal_load((const f32x4*)(Wt + (size_t)r * N_PV))
                 : z;
        }
        float vr[16];
        if (!diag) {
#pragma unroll
            for (int k = 0; k < 16; ++k) {
                const int r = rb + k;
                vr[k] = (FULL || r < nrows) ? V[rows0 + r] : 0.f;
            }
        }
        // ---- per-row partials + column accumulation (all f32) ----
        float rs[16], rd[16];
#pragma unroll
        for (int k = 0; k < 16; ++k) {
            const float w0 = w[k].x, w1 = w[k].y, w2 = w[k].z, w3 = w[k].w;
            rs[k] = (w0 + w1) + (w2 + w3);
            rd[k] = (w0 * vc.x + w1 * vc.y) + (w2 * vc.z + w3 * vc.w);
            if (!diag) {
                const float v = vr[k];
                cs0 += w0; cs1 += w1; cs2 += w2; cs3 += w3;
                cd0 += w0 * v; cd1 += w1 * v; cd2 += w2 * v; cd3 += w3 * v;
            }
        }
        // ---- batched butterfly: 16 rows, 17 shuffles per quantity ----
#pragma unroll
        for (int i = 0; i < 8; ++i) {   // dist 1: row-bit3 = b0
            const float ss = b0 ? rs[i] : rs[i + 8];
            const float sd = b0 ? rd[i] : rd[i + 8];
            const float ts = __shfl_xor(ss, 1, 64);
            const float td = __shfl_xor(sd, 1, 64);
            rs[i] = (b0 ? rs[i + 8] : rs[i]) + ts;
            rd[i] = (b0 ? rd[i + 8] : rd[i]) + td;
        }
#pragma unroll
        for (int i = 0; i < 4; ++i) {   // dist 2: row-bit2 = b1
            const float ss = b1 ? rs[i] : rs[i + 4];
            const float sd = b1 ? rd[i] : rd[i + 4];
            const float ts = __shfl_xor(ss, 2, 64);
            const float td = __shfl_xor(sd, 2, 64);
            rs[i] = (b1 ? rs[i + 4] : rs[i]) + ts;
            rd[i] = (b1 ? rd[i + 4] : rd[i]) + td;
        }
#pragma unroll
        for (int i = 0; i < 2; ++i) {   // dist 4: row-bit1 = b2
            const float ss = b2 ? rs[i] : rs[i + 2];
            const float sd = b2 ? rd[i] : rd[i + 2];
            const float ts = __shfl_xor(ss, 4, 64);
            const float td = __shfl_xor(sd, 4, 64);
            rs[i] = (b2 ? rs[i + 2] : rs[i]) + ts;
            rd[i] = (b2 ? rd[i + 2] : rd[i]) + td;
        }
        {                               // dist 8: row-bit0 = b3
            const float ss = b3 ? rs[0] : rs[1];
            const float sd = b3 ? rd[0] : rd[1];
            const float ts = __shfl_xor(ss, 8, 64);
            const float td = __shfl_xor(sd, 8, 64);
            rs[0] = (b3 ? rs[1] : rs[0]) + ts;
            rd[0] = (b3 ? rd[1] : rd[0]) + td;
        }
        rs[0] += __shfl_xor(rs[0], 16, 64);  rd[0] += __shfl_xor(rd[0], 16, 64);
        rs[0] += __shfl_xor(rs[0], 32, 64);  rd[0] += __shfl_xor(rd[0], 32, 64);

        if (lane < 16) {
            const int rl = (b0 << 3) | (b1 << 2) | (b2 << 1) | b3;  // bit-reversed lane
            const int r = rb + rl;
            if (FULL || r < nrows) {
                psum[(size_t)J * N_PV + rows0 + r] = rs[0];
                pdot[(size_t)J * N_PV + rows0 + r] = rd[0];
            }
        }
    }

    if (!diag) {
        const int c4 = 4 * lane;
        lcs[wid][c4 + 0] = cs0; lcs[wid][c4 + 1] = cs1;
        lcs[wid][c4 + 2] = cs2; lcs[wid][c4 + 3] = cs3;
        lcd[wid][c4 + 0] = cd0; lcd[wid][c4 + 1] = cd1;
        lcd[wid][c4 + 2] = cd2; lcd[wid][c4 + 3] = cd3;
        __syncthreads();
        const int c = wid * 64 + lane;   // == threadIdx.x
        if (FULL || c < ncols) {
            const float s = (lcs[0][c] + lcs[1][c]) + (lcs[2][c] + lcs[3][c]);
            const float d = (lcd[0][c] + lcd[1][c]) + (lcd[2][c] + lcd[3][c]);
            psum[(size_t)I * N_PV + cols0 + c] = s;
            pdot[(size_t)I * N_PV + cols0 + c] = d;
        }
    }
}

// ================= symmetric tile kernel =================
__global__ __launch_bounds__(256) void tile_kernel(const float* __restrict__ W,
                                                   const float* __restrict__ V,
                                                   const float* __restrict__ pv_g_exc,
                                                   float* __restrict__ psum,
                                                   float* __restrict__ pdot,
                                                   float* __restrict__ drive_p) {
    const int tid = threadIdx.x;
    const int wid = tid >> 6, lane = tid & 63;

    if (blockIdx.x == NTILES) {
        __shared__ double dls[4];
        double s = 0.0;
        for (int i = tid; i < N_PV; i += 256) s += (double)pv_g_exc[i];
        for (int off = 32; off > 0; off >>= 1) s += __shfl_down(s, off, 64);
        if (lane == 0) dls[wid] = s;
        __syncthreads();
        if (tid == 0)
            drive_p[0] = (float)(((dls[0] + dls[1]) + (dls[2] + dls[3])) / (double)N_PV);
        return;
    }

    __shared__ float lcs[4][TILE], lcd[4][TILE];   // 8 KB

    // decode linear tile index -> (I,J), J >= I
    int rem = blockIdx.x, I = 0;
    while (rem >= NT - I) { rem -= NT - I; ++I; }
    const int J = I + rem;

    const int rows0 = I * TILE, cols0 = J * TILE;
    const int nrows = min(TILE, N_PV - rows0);
    const int ncols = min(TILE, N_PV - cols0);
    const bool diag = (I == J);

    if (nrows == TILE && ncols == TILE)
        tile_body<true>(W, V, psum, pdot, I, J, rows0, cols0, nrows, ncols, diag,
                        wid, lane, lcs, lcd);
    else
        tile_body<false>(W, V, psum, pdot, I, J, rows0, cols0, nrows, ncols, diag,
                         wid, lane, lcs, lcd);
}

// ============ fallback: full-read one block per row ============
__global__ __launch_bounds__(256) void row_kernel(const float* __restrict__ W,
                                                  const float* __restrict__ V,
                                                  const float* __restrict__ pv_g_exc,
                                                  float* __restrict__ rowsum,
                                                  float* __restrict__ rowdot,
                                                  float* __restrict__ drive_p) {
    __shared__ double ls[4], ld[4];
    const int wid = threadIdx.x >> 6, lane = threadIdx.x & 63;
    const int row = blockIdx.x;
    if (row == N_PV) {
        double s = 0.0;
        for (int i = threadIdx.x; i < N_PV; i += 256) s += (double)pv_g_exc[i];
        for (int off = 32; off > 0; off >>= 1) s += __shfl_down(s, off, 64);
        if (lane == 0) ls[wid] = s;
        __syncthreads();
        if (threadIdx.x == 0)
            drive_p[0] = (float)(((ls[0] + ls[1]) + (ls[2] + ls[3])) / (double)N_PV);
        return;
    }
    const f32x4* __restrict__ wr = (const f32x4*)(W + (size_t)row * N_PV);
    const f32x4* __restrict__ vv = (const f32x4*)V;
    double s0 = 0.0, d0 = 0.0, s1 = 0.0, d1 = 0.0;
    int j = threadIdx.x;
    const int NV = N_PV / 4;
    for (; j + 256 < NV; j += 512) {
        const f32x4 w0 = __builtin_nontemporal_load(&wr[j]);
        const f32x4 v0 = vv[j];
        const f32x4 w1 = __builtin_nontemporal_load(&wr[j + 256]);
        const f32x4 v1 = vv[j + 256];
        s0 += (double)w0.x + (double)w0.y + (double)w0.z + (double)w0.w;
        d0 += (double)w0.x * (double)v0.x + (double)w0.y * (double)v0.y
            + (double)w0.z * (double)v0.z + (double)w0.w * (double)v0.w;
        s1 += (double)w1.x + (double)w1.y + (double)w1.z + (double)w1.w;
        d1 += (double)w1.x * (double)v1.x + (double)w1.y * (double)v1.y
            + (double)w1.z * (double)v1.z + (double)w1.w * (double)v1.w;
    }
    for (; j < NV; j += 256) {
        const f32x4 w0 = __builtin_nontemporal_load(&wr[j]);
        const f32x4 v0 = vv[j];
        s0 += (double)w0.x + (double)w0.y + (double)w0.z + (double)w0.w;
        d0 += (double)w0.x * (double)v0.x + (double)w0.y * (double)v0.y
            + (double)w0.z * (double)v0.z + (double)w0.w * (double)v0.w;
    }
    double s = s0 + s1, d = d0 + d1;
    for (int off = 32; off > 0; off >>= 1) {
        s += __shfl_down(s, off, 64);
        d += __shfl_down(d, off, 64);
    }
    if (lane == 0) { ls[wid] = s; ld[wid] = d; }
    __syncthreads();
    if (threadIdx.x == 0) {
        rowsum[row] = (float)((ls[0] + ls[1]) + (ls[2] + ls[3]));
        rowdot[row] = (float)((ld[0] + ld[1]) + (ld[2] + ld[3]));
    }
}

// ================= fused LIF step =================
__global__ __launch_bounds__(256) void lif_kernel(
    const float* __restrict__ pv_g_exc,  const float* __restrict__ pv_g_inh,
    const float* __restrict__ olm_g_exc, const float* __restrict__ olm_g_inh,
    const float* __restrict__ bi_g_exc,  const float* __restrict__ bi_g_inh,
    const float* __restrict__ pv_V,  const float* __restrict__ pv_tau,
    const float* __restrict__ pv_vth, const float* __restrict__ pv_gL,
    const float* __restrict__ pv_w,
    const float* __restrict__ olm_V,  const float* __restrict__ olm_tau,
    const float* __restrict__ olm_vth, const float* __restrict__ olm_gL,
    const float* __restrict__ olm_w,
    const float* __restrict__ bi_V,  const float* __restrict__ bi_tau,
    const float* __restrict__ bi_vth, const float* __restrict__ bi_gL,
    const float* __restrict__ bi_w,
    const float* __restrict__ psum, const float* __restrict__ pdot,
    const float* __restrict__ rowsum, const float* __restrict__ rowdot,
    const float* __restrict__ drive_p, int mode,
    float* __restrict__ out) {
#pragma clang fp contract(off)
    const int i = blockIdx.x * 256 + threadIdx.x;
    const float E_E = 3.0f, E_I = -0.5f, E_NMDA = 3.0f;
    if (i < N_PV) {
        float gt, rd_f;
        if (mode == 1) {
            double S = 0.0, D = 0.0;
#pragma unroll 5
            for (int s = 0; s < NT; ++s) {
                S += (double)psum[(size_t)s * N_PV + i];
                D += (double)pdot[(size_t)s * N_PV + i];
            }
            gt = (float)S; rd_f = (float)D;
        } else {
            gt = rowsum[i]; rd_f = rowdot[i];
        }
        const float drive  = drive_p[0];
        const float gain   = fminf(1.0f, drive / 0.1f);
        const float active = (drive > 0.01f) ? 1.0f : 0.0f;
        const float Egap = rd_f / (gt + 1e-9f);
        const float ggap = gt * gain * active;
        const float V   = pv_V[i];
        const float gex = pv_g_exc[i];
        const float ga  = gex * 0.7f;
        const float gn  = gex * 0.3f;
        const float gi  = pv_g_inh[i];
        const float syn = (ga * (E_E - V) + gn * (E_NMDA - V) + gi * (E_I - V)
                           + ggap * (Egap - V) - pv_w[i]) / pv_gL[i];
        const float Vn = V + (1.0f / pv_tau[i]) * ((0.0f - V) + syn);
        out[i] = (Vn >= pv_vth[i]) ? 1.0f : 0.0f;
    } else if (i < N_PV + N_OLM) {
        const int j = i - N_PV;
        const float V   = olm_V[j];
        const float gex = olm_g_exc[j];
        const float ga  = gex * 0.95f;
        const float gn  = gex * 0.05f;
        const float gi  = olm_g_inh[j];
        const float syn = (ga * (E_E - V) + gn * (E_NMDA - V) + gi * (E_I - V)
                           + 0.0f * (0.0f - V) - olm_w[j]) / olm_gL[j];
        const float Vn = V + (1.0f / olm_tau[j]) * ((0.0f - V) + syn);
        out[i] = (Vn >= olm_vth[j]) ? 1.0f : 0.0f;
    } else if (i < N_PV + N_OLM + N_BIST) {
        const int j = i - N_PV - N_OLM;
        const float V   = bi_V[j];
        const float gex = bi_g_exc[j];
        const float ga  = gex * 0.95f;
        const float gn  = gex * 0.05f;
        const float gi  = bi_g_inh[j];
        const float syn = (ga * (E_E - V) + gn * (E_NMDA - V) + gi * (E_I - V)
                           + 0.0f * (0.0f - V) - bi_w[j]) / bi_gL[j];
        const float Vn = V + (1.0f / bi_tau[j]) * ((0.0f - V) + syn);
        out[i] = (Vn >= bi_vth[j]) ? 1.0f : 0.0f;
    }
}

extern "C" void kernel_launch(void* const* d_in, const int* in_sizes, int n_in,
                              void* d_out, int out_size, void* d_ws, size_t ws_size,
                              hipStream_t stream) {
    const float* pv_g_exc   = (const float*)d_in[0];
    const float* pv_g_inh   = (const float*)d_in[1];
    const float* olm_g_exc  = (const float*)d_in[2];
    const float* olm_g_inh  = (const float*)d_in[3];
    const float* bist_g_exc = (const float*)d_in[4];
    const float* bist_g_inh = (const float*)d_in[5];
    const float* W_gap      = (const float*)d_in[6];
    const float* pv_V       = (const float*)d_in[7];
    const float* pv_tau     = (const float*)d_in[8];
    const float* pv_vth     = (const float*)d_in[9];
    const float* pv_gL      = (const float*)d_in[10];
    // d_in[11] = pv_vreset (unused: spikes don't depend on it)
    const float* pv_w       = (const float*)d_in[12];
    const float* olm_V      = (const float*)d_in[13];
    const float* olm_tau    = (const float*)d_in[14];
    const float* olm_vth    = (const float*)d_in[15];
    const float* olm_gL     = (const float*)d_in[16];
    // d_in[17] = olm_vreset (unused)
    const float* olm_w      = (const float*)d_in[18];
    const float* bist_V     = (const float*)d_in[19];
    const float* bist_tau   = (const float*)d_in[20];
    const float* bist_vth   = (const float*)d_in[21];
    const float* bist_gL    = (const float*)d_in[22];
    // d_in[23] = bist_vreset (unused)
    const float* bist_w     = (const float*)d_in[24];

    const size_t npart = (size_t)NT * N_PV;                // 770,000 floats
    const size_t need  = 2 * npart * sizeof(float) + 64;   // ~6.2 MB
    const int total = N_PV + N_OLM + N_BIST;

    if (ws_size >= need) {
        float* psum    = (float*)d_ws;
        float* pdot    = psum + npart;
        float* drive_p = pdot + npart;
        hipLaunchKernelGGL(tile_kernel, dim3(NTILES + 1), dim3(256), 0, stream,
                           W_gap, pv_V, pv_g_exc, psum, pdot, drive_p);
        hipLaunchKernelGGL(lif_kernel, dim3((total + 255) / 256), dim3(256), 0, stream,
                           pv_g_exc, pv_g_inh, olm_g_exc, olm_g_inh,
                           bist_g_exc, bist_g_inh,
                           pv_V, pv_tau, pv_vth, pv_gL, pv_w,
                           olm_V, olm_tau, olm_vth, olm_gL, olm_w,
                           bist_V, bist_tau, bist_vth, bist_gL, bist_w,
                           psum, pdot, (const float*)nullptr, (const float*)nullptr,
                           drive_p, 1, (float*)d_out);
    } else {
        float* ws      = (float*)d_ws;
        float* rowsum  = ws;
        float* rowdot  = ws + N_PV;
        float* drive_p = ws + 2 * N_PV;
        hipLaunchKernelGGL(row_kernel, dim3(N_PV + 1), dim3(256), 0, stream,
                           W_gap, pv_V, pv_g_exc, rowsum, rowdot, drive_p);
        hipLaunchKernelGGL(lif_kernel, dim3((total + 255) / 256), dim3(256), 0, stream,
                           pv_g_exc, pv_g_inh, olm_g_exc, olm_g_inh,
                           bist_g_exc, bist_g_inh,
                           pv_V, pv_tau, pv_vth, pv_gL, pv_w,
                           olm_V, olm_tau, olm_vth, olm_gL, olm_w,
                           bist_V, bist_tau, bist_vth, bist_gL, bist_w,
                           (const float*)nullptr, (const float*)nullptr,
                           rowsum, rowdot, drive_p, 0, (float*)d_out);
    }
}